// Round 1
// baseline (312.440 us; speedup 1.0000x reference)
//
#include <hip/hip_runtime.h>
#include <hip/hip_bf16.h>

typedef __bf16 bf16_t;
typedef __bf16 bf16x4 __attribute__((ext_vector_type(4)));
typedef __bf16 bf16x8 __attribute__((ext_vector_type(8)));
typedef float f32x4 __attribute__((ext_vector_type(4)));

// ---------------------------------------------------------------------------
// Weight conversion kernels: fp32 -> bf16, transposed to [N][K] row-major so
// GEMM B-fragments are contiguous (B^T input pattern, m97 structure).
// ---------------------------------------------------------------------------

// in: [H=16][C=1024][D=64] fp32 ; out: [N=H*D=1024][K=C=1024] bf16
// out[n][c] = in[h][c][d], n = h*64+d
__global__ void conv_whead(const float* __restrict__ in, bf16_t* __restrict__ out) {
    int idx = blockIdx.x * 256 + threadIdx.x;   // 262144 threads, 4 elems each
    int n  = idx >> 8;
    int c0 = (idx & 255) * 4;
    int h = n >> 6, d = n & 63;
    const float* s = in + (size_t)h * 65536 + d;
    bf16x4 v;
#pragma unroll
    for (int j = 0; j < 4; ++j) v[j] = (bf16_t)s[(size_t)(c0 + j) * 64];
    *(bf16x4*)(out + (size_t)n * 1024 + c0) = v;
}

// in: Wo [K=1024][N=1024] fp32 ; out: [N=1024][K=1024] bf16 (plain transpose)
__global__ void conv_wo(const float* __restrict__ in, bf16_t* __restrict__ out) {
    int idx = blockIdx.x * 256 + threadIdx.x;
    int n  = idx >> 8;
    int k0 = (idx & 255) * 4;
    bf16x4 v;
#pragma unroll
    for (int j = 0; j < 4; ++j) v[j] = (bf16_t)in[(size_t)(k0 + j) * 1024 + n];
    *(bf16x4*)(out + (size_t)n * 1024 + k0) = v;
}

// ---------------------------------------------------------------------------
// GEMM: C[M=4096][N=1024] = A[4096][1024] @ Bt[1024][1024]^T (+bias)
// A fp32 (converted during staging) or bf16; C fp32 or bf16.
// 128x128 tile, BK=32, 4 waves (2x2), 4x4 16x16x32 MFMA frags per wave.
// ---------------------------------------------------------------------------
template<bool A_F32, bool OUT_F32, bool BIAS>
__global__ __launch_bounds__(256, 2)
void gemm_bt(const void* __restrict__ Ap, const bf16_t* __restrict__ Bt,
             void* __restrict__ Cp, const float* __restrict__ bias) {
    constexpr int N = 1024, K = 1024, BK = 32;
    __shared__ bf16_t As[2][128][BK + 8];
    __shared__ bf16_t Bs[2][128][BK + 8];

    const int tid = threadIdx.x;
    const int m0 = blockIdx.y * 128, n0 = blockIdx.x * 128;
    const int wid = tid >> 6, ln = tid & 63;
    const int ln16 = ln & 15, g8 = (ln >> 4) * 8;
    const int wr = (wid >> 1) * 64, wc = (wid & 1) * 64;

    const float*  Af = (const float*)Ap;
    const bf16_t* Ab = (const bf16_t*)Ap;

    f32x4 zero = {0.f, 0.f, 0.f, 0.f};
    f32x4 acc[4][4];
#pragma unroll
    for (int i = 0; i < 4; ++i)
#pragma unroll
        for (int j = 0; j < 4; ++j) acc[i][j] = zero;

    auto stage = [&](int buf, int k0) {
#pragma unroll
        for (int i = 0; i < 2; ++i) {
            int c = tid + i * 256;
            int row = c >> 2, k8 = (c & 3) * 8;
            if constexpr (A_F32) {
                const float* s = Af + (size_t)(m0 + row) * K + k0 + k8;
                float4 x0 = *(const float4*)s;
                float4 x1 = *(const float4*)(s + 4);
                bf16x8 v;
                v[0] = (bf16_t)x0.x; v[1] = (bf16_t)x0.y; v[2] = (bf16_t)x0.z; v[3] = (bf16_t)x0.w;
                v[4] = (bf16_t)x1.x; v[5] = (bf16_t)x1.y; v[6] = (bf16_t)x1.z; v[7] = (bf16_t)x1.w;
                *(bf16x8*)&As[buf][row][k8] = v;
            } else {
                *(int4*)&As[buf][row][k8] =
                    *(const int4*)(Ab + (size_t)(m0 + row) * K + k0 + k8);
            }
            *(int4*)&Bs[buf][row][k8] =
                *(const int4*)(Bt + (size_t)(n0 + row) * K + k0 + k8);
        }
    };

    stage(0, 0);
    __syncthreads();
    for (int kt = 0; kt < K / BK; ++kt) {
        int cur = kt & 1;
        if (kt + 1 < K / BK) stage(cur ^ 1, (kt + 1) * BK);
        bf16x8 a[4], b[4];
#pragma unroll
        for (int i = 0; i < 4; ++i) {
            a[i] = *(const bf16x8*)&As[cur][wr + i * 16 + ln16][g8];
            b[i] = *(const bf16x8*)&Bs[cur][wc + i * 16 + ln16][g8];
        }
#pragma unroll
        for (int mi = 0; mi < 4; ++mi)
#pragma unroll
            for (int ni = 0; ni < 4; ++ni)
                acc[mi][ni] = __builtin_amdgcn_mfma_f32_16x16x32_bf16(
                    a[mi], b[ni], acc[mi][ni], 0, 0, 0);
        __syncthreads();
    }

    float*  Cf = (float*)Cp;
    bf16_t* Cb = (bf16_t*)Cp;
#pragma unroll
    for (int mi = 0; mi < 4; ++mi)
#pragma unroll
        for (int ni = 0; ni < 4; ++ni)
#pragma unroll
            for (int r = 0; r < 4; ++r) {
                int row = m0 + wr + mi * 16 + (ln >> 4) * 4 + r;
                int col = n0 + wc + ni * 16 + ln16;
                float v = acc[mi][ni][r];
                if constexpr (BIAS) v += bias[col];
                if constexpr (OUT_F32) Cf[(size_t)row * N + col] = v;
                else                   Cb[(size_t)row * N + col] = (bf16_t)v;
            }
}

// ---------------------------------------------------------------------------
// Causal flash attention.
// q/k/v layout: [B][T][H*64], head h at column offset h*64.
// Block: 4 waves, 64 q-rows (16/wave), KV tiles of 64.
// Wave-local online softmax using 16x16x32 C/D layout (row=(l>>4)*4+r, col=l&15).
// ---------------------------------------------------------------------------
__global__ __launch_bounds__(256, 2)
void attn_causal(const bf16_t* __restrict__ qp, const bf16_t* __restrict__ kp,
                 const bf16_t* __restrict__ vp, bf16_t* __restrict__ op) {
    constexpr int T = 2048, HC = 1024;
    __shared__ bf16_t Ks[64][72];      // K tile [s][d], +8 pad
    __shared__ bf16_t Vt[64][72];      // V^T tile [d->n][s]
    __shared__ bf16_t Ps[4][16][72];   // per-wave P tile [r][s]

    const int tid = threadIdx.x;
    const int wid = tid >> 6, ln = tid & 63;
    const int ln16 = ln & 15, g = ln >> 4, g8 = g * 8;
    const int q0 = blockIdx.x * 64;
    const int bh = blockIdx.y;                       // b*16 + h
    const size_t base = (size_t)(bh >> 4) * T * HC + (size_t)(bh & 15) * 64;
    const bf16_t* Q  = qp + base;
    const bf16_t* Kg = kp + base;
    const bf16_t* Vg = vp + base;

    const int r0 = q0 + wid * 16;
    const int rowb = r0 + g * 4;

    bf16x8 qf0 = *(const bf16x8*)(Q + (size_t)(r0 + ln16) * HC + g8);
    bf16x8 qf1 = *(const bf16x8*)(Q + (size_t)(r0 + ln16) * HC + 32 + g8);

    float m[4], lsum[4];
    f32x4 zero = {0.f, 0.f, 0.f, 0.f};
    f32x4 oacc[4];
#pragma unroll
    for (int r = 0; r < 4; ++r) { m[r] = -3.0e38f; lsum[r] = 0.f; oacc[r] = zero; }

    for (int kv0 = 0; kv0 <= q0; kv0 += 64) {
        __syncthreads();
        // cooperative staging of K tile and transposed V tile
#pragma unroll
        for (int i = 0; i < 2; ++i) {
            int c = tid + i * 256;
            int row = c >> 3, c8 = (c & 7) * 8;
            *(int4*)&Ks[row][c8] =
                *(const int4*)(Kg + (size_t)(kv0 + row) * HC + c8);
            int4 vv = *(const int4*)(Vg + (size_t)(kv0 + row) * HC + c8);
            const bf16_t* vb = (const bf16_t*)&vv;
#pragma unroll
            for (int j = 0; j < 8; ++j) Vt[c8 + j][row] = vb[j];
        }
        __syncthreads();

        // S = Q K^T for this wave's 16 rows x 64 cols
        f32x4 s[4];
#pragma unroll
        for (int cg = 0; cg < 4; ++cg) {
            bf16x8 kf0 = *(const bf16x8*)&Ks[cg * 16 + ln16][g8];
            bf16x8 kf1 = *(const bf16x8*)&Ks[cg * 16 + ln16][32 + g8];
            f32x4 z = zero;
            z = __builtin_amdgcn_mfma_f32_16x16x32_bf16(qf0, kf0, z, 0, 0, 0);
            z = __builtin_amdgcn_mfma_f32_16x16x32_bf16(qf1, kf1, z, 0, 0, 0);
            s[cg] = z;
        }

        // scale + causal mask (only the diagonal tile needs masking)
        float zv[4][4];
        const bool diag = (kv0 == q0);
#pragma unroll
        for (int cg = 0; cg < 4; ++cg) {
            int col = kv0 + cg * 16 + ln16;
#pragma unroll
            for (int r = 0; r < 4; ++r) {
                float v = s[cg][r] * 0.125f;
                if (diag && col > rowb + r) v = -1.0e30f;
                zv[cg][r] = v;
            }
        }

        // online softmax update (row reduce across the 16-lane group)
#pragma unroll
        for (int r = 0; r < 4; ++r) {
            float mx = fmaxf(fmaxf(zv[0][r], zv[1][r]), fmaxf(zv[2][r], zv[3][r]));
            mx = fmaxf(mx, __shfl_xor(mx, 1, 64));
            mx = fmaxf(mx, __shfl_xor(mx, 2, 64));
            mx = fmaxf(mx, __shfl_xor(mx, 4, 64));
            mx = fmaxf(mx, __shfl_xor(mx, 8, 64));
            float newm = fmaxf(m[r], mx);
            float alpha = __expf(m[r] - newm);
            float psum = 0.f;
#pragma unroll
            for (int cg = 0; cg < 4; ++cg) {
                float p = __expf(zv[cg][r] - newm);
                zv[cg][r] = p;
                psum += p;
            }
            psum += __shfl_xor(psum, 1, 64);
            psum += __shfl_xor(psum, 2, 64);
            psum += __shfl_xor(psum, 4, 64);
            psum += __shfl_xor(psum, 8, 64);
            lsum[r] = lsum[r] * alpha + psum;
            m[r] = newm;
#pragma unroll
            for (int nf = 0; nf < 4; ++nf) oacc[nf][r] *= alpha;
        }

        // P -> per-wave LDS (bf16), reshape C/D layout -> A layout
#pragma unroll
        for (int cg = 0; cg < 4; ++cg)
#pragma unroll
            for (int r = 0; r < 4; ++r)
                Ps[wid][g * 4 + r][cg * 16 + ln16] = (bf16_t)zv[cg][r];

        // O += P @ V
#pragma unroll
        for (int kc = 0; kc < 2; ++kc) {
            bf16x8 pa = *(const bf16x8*)&Ps[wid][ln16][kc * 32 + g8];
#pragma unroll
            for (int nf = 0; nf < 4; ++nf) {
                bf16x8 vf = *(const bf16x8*)&Vt[nf * 16 + ln16][kc * 32 + g8];
                oacc[nf] = __builtin_amdgcn_mfma_f32_16x16x32_bf16(pa, vf, oacc[nf], 0, 0, 0);
            }
        }
    }

    bf16_t* O = op + base;
#pragma unroll
    for (int nf = 0; nf < 4; ++nf)
#pragma unroll
        for (int r = 0; r < 4; ++r) {
            float v = oacc[nf][r] / lsum[r];
            O[(size_t)(r0 + g * 4 + r) * HC + nf * 16 + ln16] = (bf16_t)v;
        }
}

// ---------------------------------------------------------------------------

extern "C" void kernel_launch(void* const* d_in, const int* in_sizes, int n_in,
                              void* d_out, int out_size, void* d_ws, size_t ws_size,
                              hipStream_t stream) {
    const float* K_in = (const float*)d_in[0];
    const float* Q_in = (const float*)d_in[1];
    const float* V_in = (const float*)d_in[2];
    const float* Wk   = (const float*)d_in[3];
    const float* Wq   = (const float*)d_in[4];
    const float* Wv   = (const float*)d_in[5];
    const float* Wo   = (const float*)d_in[6];
    const float* bo   = (const float*)d_in[7];

    char* ws = (char*)d_ws;
    const size_t MB = 1024 * 1024;
    bf16_t* Wqt = (bf16_t*)(ws + 0 * MB);
    bf16_t* Wkt = (bf16_t*)(ws + 2 * MB);
    bf16_t* Wvt = (bf16_t*)(ws + 4 * MB);
    bf16_t* Wot = (bf16_t*)(ws + 6 * MB);
    bf16_t* qp  = (bf16_t*)(ws + 8 * MB);
    bf16_t* kp  = (bf16_t*)(ws + 16 * MB);
    bf16_t* vp  = (bf16_t*)(ws + 24 * MB);
    bf16_t* ao  = (bf16_t*)(ws + 32 * MB);   // total 40 MB

    conv_whead<<<1024, 256, 0, stream>>>(Wq, Wqt);
    conv_whead<<<1024, 256, 0, stream>>>(Wk, Wkt);
    conv_whead<<<1024, 256, 0, stream>>>(Wv, Wvt);
    conv_wo  <<<1024, 256, 0, stream>>>(Wo, Wot);

    dim3 gg(8, 32);   // N/128, M/128
    gemm_bt<true, false, false><<<gg, 256, 0, stream>>>(Q_in, Wqt, qp, nullptr);
    gemm_bt<true, false, false><<<gg, 256, 0, stream>>>(K_in, Wkt, kp, nullptr);
    gemm_bt<true, false, false><<<gg, 256, 0, stream>>>(V_in, Wvt, vp, nullptr);

    attn_causal<<<dim3(32, 32), 256, 0, stream>>>(qp, kp, vp, ao);

    gemm_bt<false, true, true><<<gg, 256, 0, stream>>>(ao, Wot, d_out, bo);
}

// Round 3
// 233.332 us; speedup vs baseline: 1.3390x; 1.3390x over previous
//
#include <hip/hip_runtime.h>
#include <hip/hip_bf16.h>

typedef __bf16 bf16_t;
typedef __bf16 bf16x4 __attribute__((ext_vector_type(4)));
typedef __bf16 bf16x8 __attribute__((ext_vector_type(8)));
typedef float f32x4 __attribute__((ext_vector_type(4)));
typedef unsigned int u32;

static __device__ __forceinline__ u32 pk2(float a, float b) {
    union { u32 u; bf16_t h[2]; } w;
    w.h[0] = (bf16_t)a; w.h[1] = (bf16_t)b;
    return w.u;
}

// ---------------------------------------------------------------------------
// Weight conversion: fp32 -> bf16, to [N][K] (B^T) layout.
// ---------------------------------------------------------------------------
__global__ void conv_whead(const float* __restrict__ in, bf16_t* __restrict__ out) {
    int idx = blockIdx.x * 256 + threadIdx.x;
    int n  = idx >> 8;
    int c0 = (idx & 255) * 4;
    int h = n >> 6, d = n & 63;
    const float* s = in + (size_t)h * 65536 + d;
    bf16x4 v;
#pragma unroll
    for (int j = 0; j < 4; ++j) v[j] = (bf16_t)s[(size_t)(c0 + j) * 64];
    *(bf16x4*)(out + (size_t)n * 1024 + c0) = v;
}

__global__ void conv_wo(const float* __restrict__ in, bf16_t* __restrict__ out) {
    int idx = blockIdx.x * 256 + threadIdx.x;
    int n  = idx >> 8;
    int k0 = (idx & 255) * 4;
    bf16x4 v;
#pragma unroll
    for (int j = 0; j < 4; ++j) v[j] = (bf16_t)in[(size_t)(k0 + j) * 1024 + n];
    *(bf16x4*)(out + (size_t)n * 1024 + k0) = v;
}

// ---------------------------------------------------------------------------
// GEMM core: C[M][1024] = A[M][1024] @ Bt[1024][1024]^T (+bias)
// BM x 128 tile, BK=32, 4 waves (2x2), 16x16x32 MFMA.
// ---------------------------------------------------------------------------
template<int BM, bool A_F32, bool OUT_F32, bool BIAS>
__device__ __forceinline__
void gemm_core(const void* Ap, const bf16_t* Bt, void* Cp, const float* bias,
               int m0, int n0) {
    constexpr int N = 1024, K = 1024, BK = 32;
    constexpr int MI = BM / 32;          // m-frags per wave
    constexpr int AL = BM / 64;          // A int4 loads per thread
    __shared__ bf16_t As[2][BM][BK + 8];
    __shared__ bf16_t Bs[2][128][BK + 8];

    const int tid = threadIdx.x;
    const int wid = tid >> 6, ln = tid & 63;
    const int ln16 = ln & 15, g8 = (ln >> 4) * 8;
    const int wr = (wid >> 1) * (BM / 2), wc = (wid & 1) * 64;

    const float*  Af = (const float*)Ap;
    const bf16_t* Ab = (const bf16_t*)Ap;

    f32x4 zero = {0.f, 0.f, 0.f, 0.f};
    f32x4 acc[MI][4];
#pragma unroll
    for (int i = 0; i < MI; ++i)
#pragma unroll
        for (int j = 0; j < 4; ++j) acc[i][j] = zero;

    auto stage = [&](int buf, int k0) {
#pragma unroll
        for (int i = 0; i < AL; ++i) {
            int c = tid + i * 256;
            int row = c >> 2, k8 = (c & 3) * 8;
            if constexpr (A_F32) {
                const float* s = Af + (size_t)(m0 + row) * K + k0 + k8;
                float4 x0 = *(const float4*)s;
                float4 x1 = *(const float4*)(s + 4);
                bf16x8 v;
                v[0] = (bf16_t)x0.x; v[1] = (bf16_t)x0.y; v[2] = (bf16_t)x0.z; v[3] = (bf16_t)x0.w;
                v[4] = (bf16_t)x1.x; v[5] = (bf16_t)x1.y; v[6] = (bf16_t)x1.z; v[7] = (bf16_t)x1.w;
                *(bf16x8*)&As[buf][row][k8] = v;
            } else {
                *(int4*)&As[buf][row][k8] =
                    *(const int4*)(Ab + (size_t)(m0 + row) * K + k0 + k8);
            }
        }
#pragma unroll
        for (int i = 0; i < 2; ++i) {
            int c = tid + i * 256;
            int row = c >> 2, k8 = (c & 3) * 8;
            *(int4*)&Bs[buf][row][k8] =
                *(const int4*)(Bt + (size_t)(n0 + row) * K + k0 + k8);
        }
    };

    stage(0, 0);
    __syncthreads();
    for (int kt = 0; kt < K / BK; ++kt) {
        int cur = kt & 1;
        if (kt + 1 < K / BK) stage(cur ^ 1, (kt + 1) * BK);
        bf16x8 a[MI], b[4];
#pragma unroll
        for (int i = 0; i < MI; ++i)
            a[i] = *(const bf16x8*)&As[cur][wr + i * 16 + ln16][g8];
#pragma unroll
        for (int i = 0; i < 4; ++i)
            b[i] = *(const bf16x8*)&Bs[cur][wc + i * 16 + ln16][g8];
#pragma unroll
        for (int mi = 0; mi < MI; ++mi)
#pragma unroll
            for (int ni = 0; ni < 4; ++ni)
                acc[mi][ni] = __builtin_amdgcn_mfma_f32_16x16x32_bf16(
                    a[mi], b[ni], acc[mi][ni], 0, 0, 0);
        __syncthreads();
    }

    float*  Cf = (float*)Cp;
    bf16_t* Cb = (bf16_t*)Cp;
#pragma unroll
    for (int mi = 0; mi < MI; ++mi)
#pragma unroll
        for (int ni = 0; ni < 4; ++ni)
#pragma unroll
            for (int r = 0; r < 4; ++r) {
                int row = m0 + wr + mi * 16 + (ln >> 4) * 4 + r;
                int col = n0 + wc + ni * 16 + ln16;
                float v = acc[mi][ni][r];
                if constexpr (BIAS) v += bias[col];
                if constexpr (OUT_F32) Cf[(size_t)row * N + col] = v;
                else                   Cb[(size_t)row * N + col] = (bf16_t)v;
            }
}

// z-fused projection GEMM: 3 independent (A fp32, Bt, C bf16) triples.
__global__ __launch_bounds__(256, 3)
void gemm_proj(const float* A0, const float* A1, const float* A2,
               const bf16_t* B0, const bf16_t* B1, const bf16_t* B2,
               bf16_t* C0, bf16_t* C1, bf16_t* C2) {
    int z = blockIdx.z;
    const float* A = (z == 0) ? A0 : (z == 1) ? A1 : A2;
    const bf16_t* B = (z == 0) ? B0 : (z == 1) ? B1 : B2;
    bf16_t* C = (z == 0) ? C0 : (z == 1) ? C1 : C2;
    gemm_core<128, true, false, false>(A, B, C, nullptr,
                                       blockIdx.y * 128, blockIdx.x * 128);
}

// final output GEMM: A bf16, out fp32 + bias; BM=64 tiles for occupancy.
__global__ __launch_bounds__(256, 4)
void gemm_out(const bf16_t* A, const bf16_t* Bt, void* C, const float* bias) {
    gemm_core<64, false, true, true>(A, Bt, C, bias,
                                     blockIdx.y * 64, blockIdx.x * 128);
}

// ---------------------------------------------------------------------------
// Transpose v [B][T][HC] -> vt [B][HC][T] (64x64 LDS tiles).
// ---------------------------------------------------------------------------
__global__ void transpose_bf16(const bf16_t* __restrict__ in, bf16_t* __restrict__ out) {
    __shared__ bf16_t t[64][72];
    const int b = blockIdx.z;
    const int r0 = blockIdx.x * 64;   // token rows
    const int c0 = blockIdx.y * 64;   // feature cols
    const bf16_t* src = in + (size_t)b * 2048 * 1024;
    bf16_t* dst = out + (size_t)b * 1024 * 2048;
    const int tid = threadIdx.x;
    const int row = tid >> 3, c8 = (tid & 7) * 8;
#pragma unroll
    for (int i = 0; i < 2; ++i)
        *(int4*)&t[row + i * 32][c8] =
            *(const int4*)(src + (size_t)(r0 + row + i * 32) * 1024 + c0 + c8);
    __syncthreads();
#pragma unroll
    for (int i = 0; i < 2; ++i) {
        int orow = row + i * 32;   // feature index within tile
        bf16x8 v;
#pragma unroll
        for (int j = 0; j < 8; ++j) v[j] = t[c8 + j][orow];
        *(bf16x8*)(dst + (size_t)(c0 + orow) * 2048 + r0 + c8) = v;
    }
}

// ---------------------------------------------------------------------------
// Causal flash attention, swapped-QK^T in-register softmax.
// q,k: [B][T][HC] (head h at col h*64). vt: [B][HC][T] (V^T).
// Block: 4 waves x 16 q-rows = 64 q-rows; KV tiles of 64.
// ---------------------------------------------------------------------------
__global__ __launch_bounds__(256, 4)
void attn_causal(const bf16_t* __restrict__ qp, const bf16_t* __restrict__ kp,
                 const bf16_t* __restrict__ vtp, bf16_t* __restrict__ op) {
    constexpr int T = 2048, HC = 1024;
    __shared__ bf16_t Ks[64][72];   // K tile  [s][d]
    __shared__ bf16_t Vs[64][72];   // V^T tile [d][s]

    const int tid = threadIdx.x;
    const int wid = tid >> 6, ln = tid & 63;
    const int q16 = ln & 15, g = ln >> 4, g8 = g * 8;
    const int bh = blockIdx.x;            // b*16 + h  (x = bh for load balance)
    const int q0 = blockIdx.y * 64;
    const int b = bh >> 4, h = bh & 15;
    const bf16_t* Q  = qp  + (size_t)b * T * HC + (size_t)h * 64;
    const bf16_t* Kg = kp  + (size_t)b * T * HC + (size_t)h * 64;
    const bf16_t* Vt = vtp + (size_t)b * HC * T + (size_t)h * 64 * T;
    const int r0 = q0 + wid * 16;
    const int qrow = r0 + q16;            // this lane's q row

    bf16x8 qf0 = *(const bf16x8*)(Q + (size_t)qrow * HC + g8);
    bf16x8 qf1 = *(const bf16x8*)(Q + (size_t)qrow * HC + 32 + g8);

    const int srow = tid >> 3, sc8 = (tid & 7) * 8;   // staging map

    float mrow = -3.0e38f, lrow = 0.f;
    f32x4 zero = {0.f, 0.f, 0.f, 0.f};
    f32x4 oacc[4];
#pragma unroll
    for (int i = 0; i < 4; ++i) oacc[i] = zero;

    const int ntiles = q0 / 64 + 1;
    int4 kreg[2], vreg[2];

    auto ldtile = [&](int t) {
        int kv = t * 64;
#pragma unroll
        for (int i = 0; i < 2; ++i) {
            kreg[i] = *(const int4*)(Kg + (size_t)(kv + srow + i * 32) * HC + sc8);
            vreg[i] = *(const int4*)(Vt + (size_t)(srow + i * 32) * T + kv + sc8);
        }
    };
    auto wrtile = [&]() {
#pragma unroll
        for (int i = 0; i < 2; ++i) {
            *(int4*)&Ks[srow + i * 32][sc8] = kreg[i];
            *(int4*)&Vs[srow + i * 32][sc8] = vreg[i];
        }
    };

    ldtile(0);
    wrtile();
    __syncthreads();

    for (int t = 0; t < ntiles; ++t) {
        const int kv0 = t * 64;
        if (t + 1 < ntiles) ldtile(t + 1);   // prefetch (latency hidden under compute)

        // S^T = K Q^T : lane holds S[s = kv0+sb*16+4g+r][q = qrow]
        float p[4][4];
#pragma unroll
        for (int sb = 0; sb < 4; ++sb) {
            bf16x8 kf0 = *(const bf16x8*)&Ks[sb * 16 + q16][g8];
            bf16x8 kf1 = *(const bf16x8*)&Ks[sb * 16 + q16][32 + g8];
            f32x4 z = zero;
            z = __builtin_amdgcn_mfma_f32_16x16x32_bf16(kf0, qf0, z, 0, 0, 0);
            z = __builtin_amdgcn_mfma_f32_16x16x32_bf16(kf1, qf1, z, 0, 0, 0);
            int sbase = kv0 + sb * 16 + 4 * g;
#pragma unroll
            for (int r = 0; r < 4; ++r)
                p[sb][r] = (sbase + r <= qrow) ? z[r] * 0.125f : -1.0e30f;
        }

        // in-register online softmax for row qrow (spread over 4 lanes)
        float mx = -3.0e38f;
#pragma unroll
        for (int sb = 0; sb < 4; ++sb)
#pragma unroll
            for (int r = 0; r < 4; ++r) mx = fmaxf(mx, p[sb][r]);
        mx = fmaxf(mx, __shfl_xor(mx, 16, 64));
        mx = fmaxf(mx, __shfl_xor(mx, 32, 64));
        float newm = fmaxf(mrow, mx);
        float alpha = __expf(mrow - newm);
        mrow = newm;
        float psum = 0.f;
#pragma unroll
        for (int sb = 0; sb < 4; ++sb)
#pragma unroll
            for (int r = 0; r < 4; ++r) {
                float e = __expf(p[sb][r] - newm);
                p[sb][r] = e;
                psum += e;
            }
        psum += __shfl_xor(psum, 16, 64);
        psum += __shfl_xor(psum, 32, 64);
        lrow = lrow * alpha + psum;

        // rescale O (rows q = r0 + 4g + r need alpha of that row's lane)
        float arow[4];
#pragma unroll
        for (int r = 0; r < 4; ++r) arow[r] = __shfl(alpha, 4 * g + r, 64);
#pragma unroll
        for (int nf = 0; nf < 4; ++nf)
#pragma unroll
            for (int r = 0; r < 4; ++r) oacc[nf][r] *= arow[r];

        // pack P to bf16 dwords, exchange to PV A-fragment layout
        u32 W0[4], W1[4];
#pragma unroll
        for (int sb = 0; sb < 4; ++sb) {
            W0[sb] = pk2(p[sb][0], p[sb][1]);
            W1[sb] = pk2(p[sb][2], p[sb][3]);
        }
        const int h1 = ((2 * g) & 3) * 16 + q16;
        const int h2 = ((2 * g + 1) & 3) * 16 + q16;
        const bool ghi = (g & 2) != 0;
        u32 fr[2][4];
#pragma unroll
        for (int kc = 0; kc < 2; ++kc) {
            u32 aa = (u32)__shfl((int)W0[2 * kc], h1, 64);
            u32 ab = (u32)__shfl((int)W0[2 * kc + 1], h1, 64);
            u32 ba = (u32)__shfl((int)W1[2 * kc], h1, 64);
            u32 bb = (u32)__shfl((int)W1[2 * kc + 1], h1, 64);
            u32 ca = (u32)__shfl((int)W0[2 * kc], h2, 64);
            u32 cb = (u32)__shfl((int)W0[2 * kc + 1], h2, 64);
            u32 da = (u32)__shfl((int)W1[2 * kc], h2, 64);
            u32 db = (u32)__shfl((int)W1[2 * kc + 1], h2, 64);
            fr[kc][0] = ghi ? ab : aa;
            fr[kc][1] = ghi ? bb : ba;
            fr[kc][2] = ghi ? cb : ca;
            fr[kc][3] = ghi ? db : da;
        }

        // O += P V  (a = P[q][s], b = V^T[dv][s])
#pragma unroll
        for (int kc = 0; kc < 2; ++kc) {
            union { u32 u[4]; bf16x8 v; } cv;
#pragma unroll
            for (int i = 0; i < 4; ++i) cv.u[i] = fr[kc][i];
            bf16x8 pa = cv.v;
#pragma unroll
            for (int nf = 0; nf < 4; ++nf) {
                bf16x8 vf = *(const bf16x8*)&Vs[nf * 16 + q16][kc * 32 + g8];
                oacc[nf] = __builtin_amdgcn_mfma_f32_16x16x32_bf16(pa, vf, oacc[nf], 0, 0, 0);
            }
        }

        if (t + 1 < ntiles) {
            __syncthreads();
            wrtile();
            __syncthreads();
        }
    }

    bf16_t* O = op + (size_t)b * T * HC + (size_t)h * 64;
#pragma unroll
    for (int r = 0; r < 4; ++r) {
        float lr = __shfl(lrow, 4 * g + r, 64);
        float inv = 1.0f / lr;
#pragma unroll
        for (int nf = 0; nf < 4; ++nf)
            O[(size_t)(r0 + 4 * g + r) * HC + nf * 16 + q16] = (bf16_t)(oacc[nf][r] * inv);
    }
}

// ---------------------------------------------------------------------------

extern "C" void kernel_launch(void* const* d_in, const int* in_sizes, int n_in,
                              void* d_out, int out_size, void* d_ws, size_t ws_size,
                              hipStream_t stream) {
    const float* K_in = (const float*)d_in[0];
    const float* Q_in = (const float*)d_in[1];
    const float* V_in = (const float*)d_in[2];
    const float* Wk   = (const float*)d_in[3];
    const float* Wq   = (const float*)d_in[4];
    const float* Wv   = (const float*)d_in[5];
    const float* Wo   = (const float*)d_in[6];
    const float* bo   = (const float*)d_in[7];

    char* ws = (char*)d_ws;
    const size_t MB = 1024 * 1024;
    bf16_t* Wqt = (bf16_t*)(ws + 0 * MB);
    bf16_t* Wkt = (bf16_t*)(ws + 2 * MB);
    bf16_t* Wvt = (bf16_t*)(ws + 4 * MB);
    bf16_t* Wot = (bf16_t*)(ws + 6 * MB);
    bf16_t* qp  = (bf16_t*)(ws + 8 * MB);
    bf16_t* kp  = (bf16_t*)(ws + 16 * MB);
    bf16_t* vp  = (bf16_t*)(ws + 24 * MB);
    bf16_t* vt  = (bf16_t*)(ws + 32 * MB);
    bf16_t* ao  = (bf16_t*)(ws + 24 * MB);   // reuse vp after transpose; 40 MB total

    conv_whead<<<1024, 256, 0, stream>>>(Wq, Wqt);
    conv_whead<<<1024, 256, 0, stream>>>(Wk, Wkt);
    conv_whead<<<1024, 256, 0, stream>>>(Wv, Wvt);
    conv_wo  <<<1024, 256, 0, stream>>>(Wo, Wot);

    gemm_proj<<<dim3(8, 32, 3), 256, 0, stream>>>(Q_in, K_in, V_in,
                                                  Wqt, Wkt, Wvt,
                                                  qp, kp, vp);

    transpose_bf16<<<dim3(32, 16, 2), 256, 0, stream>>>(vp, vt);

    attn_causal<<<dim3(32, 32), 256, 0, stream>>>(qp, kp, vt, ao);

    gemm_out<<<dim3(8, 64), 256, 0, stream>>>(ao, Wot, d_out, bo);
}

// Round 4
// 214.492 us; speedup vs baseline: 1.4566x; 1.0878x over previous
//
#include <hip/hip_runtime.h>
#include <hip/hip_bf16.h>

typedef __bf16 bf16_t;
typedef __bf16 bf16x4 __attribute__((ext_vector_type(4)));
typedef __bf16 bf16x8 __attribute__((ext_vector_type(8)));
typedef float f32x4 __attribute__((ext_vector_type(4)));
typedef unsigned int u32;

static __device__ __forceinline__ u32 pk2(float a, float b) {
    union { u32 u; bf16_t h[2]; } w;
    w.h[0] = (bf16_t)a; w.h[1] = (bf16_t)b;
    return w.u;
}

// ---------------------------------------------------------------------------
// Weight conversion: fp32 -> bf16, to [N][K] (B^T) layout.
// ---------------------------------------------------------------------------
__global__ void conv_whead(const float* __restrict__ in, bf16_t* __restrict__ out) {
    int idx = blockIdx.x * 256 + threadIdx.x;
    int n  = idx >> 8;
    int c0 = (idx & 255) * 4;
    int h = n >> 6, d = n & 63;
    const float* s = in + (size_t)h * 65536 + d;
    bf16x4 v;
#pragma unroll
    for (int j = 0; j < 4; ++j) v[j] = (bf16_t)s[(size_t)(c0 + j) * 64];
    *(bf16x4*)(out + (size_t)n * 1024 + c0) = v;
}

__global__ void conv_wo(const float* __restrict__ in, bf16_t* __restrict__ out) {
    int idx = blockIdx.x * 256 + threadIdx.x;
    int n  = idx >> 8;
    int k0 = (idx & 255) * 4;
    bf16x4 v;
#pragma unroll
    for (int j = 0; j < 4; ++j) v[j] = (bf16_t)in[(size_t)(k0 + j) * 1024 + n];
    *(bf16x4*)(out + (size_t)n * 1024 + k0) = v;
}

// ---------------------------------------------------------------------------
// GEMM core: C[M][1024] = A[M][1024] @ Bt[1024][1024]^T (+bias)
// ---------------------------------------------------------------------------
template<int BM, bool A_F32, bool OUT_F32, bool BIAS>
__device__ __forceinline__
void gemm_core(const void* Ap, const bf16_t* Bt, void* Cp, const float* bias,
               int m0, int n0) {
    constexpr int N = 1024, K = 1024, BK = 32;
    constexpr int MI = BM / 32;
    constexpr int AL = BM / 64;
    __shared__ bf16_t As[2][BM][BK + 8];
    __shared__ bf16_t Bs[2][128][BK + 8];

    const int tid = threadIdx.x;
    const int wid = tid >> 6, ln = tid & 63;
    const int ln16 = ln & 15, g8 = (ln >> 4) * 8;
    const int wr = (wid >> 1) * (BM / 2), wc = (wid & 1) * 64;

    const float*  Af = (const float*)Ap;
    const bf16_t* Ab = (const bf16_t*)Ap;

    f32x4 zero = {0.f, 0.f, 0.f, 0.f};
    f32x4 acc[MI][4];
#pragma unroll
    for (int i = 0; i < MI; ++i)
#pragma unroll
        for (int j = 0; j < 4; ++j) acc[i][j] = zero;

    auto stage = [&](int buf, int k0) {
#pragma unroll
        for (int i = 0; i < AL; ++i) {
            int c = tid + i * 256;
            int row = c >> 2, k8 = (c & 3) * 8;
            if constexpr (A_F32) {
                const float* s = Af + (size_t)(m0 + row) * K + k0 + k8;
                float4 x0 = *(const float4*)s;
                float4 x1 = *(const float4*)(s + 4);
                bf16x8 v;
                v[0] = (bf16_t)x0.x; v[1] = (bf16_t)x0.y; v[2] = (bf16_t)x0.z; v[3] = (bf16_t)x0.w;
                v[4] = (bf16_t)x1.x; v[5] = (bf16_t)x1.y; v[6] = (bf16_t)x1.z; v[7] = (bf16_t)x1.w;
                *(bf16x8*)&As[buf][row][k8] = v;
            } else {
                *(int4*)&As[buf][row][k8] =
                    *(const int4*)(Ab + (size_t)(m0 + row) * K + k0 + k8);
            }
        }
#pragma unroll
        for (int i = 0; i < 2; ++i) {
            int c = tid + i * 256;
            int row = c >> 2, k8 = (c & 3) * 8;
            *(int4*)&Bs[buf][row][k8] =
                *(const int4*)(Bt + (size_t)(n0 + row) * K + k0 + k8);
        }
    };

    stage(0, 0);
    __syncthreads();
    for (int kt = 0; kt < K / BK; ++kt) {
        int cur = kt & 1;
        if (kt + 1 < K / BK) stage(cur ^ 1, (kt + 1) * BK);
        bf16x8 a[MI], b[4];
#pragma unroll
        for (int i = 0; i < MI; ++i)
            a[i] = *(const bf16x8*)&As[cur][wr + i * 16 + ln16][g8];
#pragma unroll
        for (int i = 0; i < 4; ++i)
            b[i] = *(const bf16x8*)&Bs[cur][wc + i * 16 + ln16][g8];
#pragma unroll
        for (int mi = 0; mi < MI; ++mi)
#pragma unroll
            for (int ni = 0; ni < 4; ++ni)
                acc[mi][ni] = __builtin_amdgcn_mfma_f32_16x16x32_bf16(
                    a[mi], b[ni], acc[mi][ni], 0, 0, 0);
        __syncthreads();
    }

    float*  Cf = (float*)Cp;
    bf16_t* Cb = (bf16_t*)Cp;
#pragma unroll
    for (int mi = 0; mi < MI; ++mi)
#pragma unroll
        for (int ni = 0; ni < 4; ++ni)
#pragma unroll
            for (int r = 0; r < 4; ++r) {
                int row = m0 + wr + mi * 16 + (ln >> 4) * 4 + r;
                int col = n0 + wc + ni * 16 + ln16;
                float v = acc[mi][ni][r];
                if constexpr (BIAS) v += bias[col];
                if constexpr (OUT_F32) Cf[(size_t)row * N + col] = v;
                else                   Cb[(size_t)row * N + col] = (bf16_t)v;
            }
}

__global__ __launch_bounds__(256, 3)
void gemm_proj(const float* A0, const float* A1, const float* A2,
               const bf16_t* B0, const bf16_t* B1, const bf16_t* B2,
               bf16_t* C0, bf16_t* C1, bf16_t* C2) {
    int z = blockIdx.z;
    const float* A = (z == 0) ? A0 : (z == 1) ? A1 : A2;
    const bf16_t* B = (z == 0) ? B0 : (z == 1) ? B1 : B2;
    bf16_t* C = (z == 0) ? C0 : (z == 1) ? C1 : C2;
    gemm_core<128, true, false, false>(A, B, C, nullptr,
                                       blockIdx.y * 128, blockIdx.x * 128);
}

__global__ __launch_bounds__(256, 4)
void gemm_out(const bf16_t* A, const bf16_t* Bt, void* C, const float* bias) {
    gemm_core<64, false, true, true>(A, Bt, C, bias,
                                     blockIdx.y * 64, blockIdx.x * 128);
}

// ---------------------------------------------------------------------------
// Transpose v [B][T][HC] -> vt [B][HC][T]
// ---------------------------------------------------------------------------
__global__ void transpose_bf16(const bf16_t* __restrict__ in, bf16_t* __restrict__ out) {
    __shared__ bf16_t t[64][72];
    const int b = blockIdx.z;
    const int r0 = blockIdx.x * 64;
    const int c0 = blockIdx.y * 64;
    const bf16_t* src = in + (size_t)b * 2048 * 1024;
    bf16_t* dst = out + (size_t)b * 1024 * 2048;
    const int tid = threadIdx.x;
    const int row = tid >> 3, c8 = (tid & 7) * 8;
#pragma unroll
    for (int i = 0; i < 2; ++i)
        *(int4*)&t[row + i * 32][c8] =
            *(const int4*)(src + (size_t)(r0 + row + i * 32) * 1024 + c0 + c8);
    __syncthreads();
#pragma unroll
    for (int i = 0; i < 2; ++i) {
        int orow = row + i * 32;
        bf16x8 v;
#pragma unroll
        for (int j = 0; j < 8; ++j) v[j] = t[c8 + j][orow];
        *(bf16x8*)(dst + (size_t)(c0 + orow) * 2048 + r0 + c8) = v;
    }
}

// ---------------------------------------------------------------------------
// Causal flash attention v2: KVBLK=128, 2 q-strips/wave (32 q-rows),
// LDS P-routing (wave-local), defer-max, exp2 domain, XCD-chunked bh map.
// Block: 4 waves, 128 q-rows. Grid: 512 blocks (8 xcd x 4 bh x 16 qsuper).
// ---------------------------------------------------------------------------
__global__ __launch_bounds__(256, 2)
void attn_causal(const bf16_t* __restrict__ qp, const bf16_t* __restrict__ kp,
                 const bf16_t* __restrict__ vtp, bf16_t* __restrict__ op) {
    constexpr int T = 2048, HC = 1024;
    constexpr float SC2 = 0.18033688011112042f;   // 0.125 * log2(e)
    constexpr float THR = 7.0f;
    __shared__ bf16_t Ks[128][72];    // K tile  [s][d]
    __shared__ bf16_t Vs[64][136];    // V^T tile [d][s]
    __shared__ bf16_t Pex[128][136];  // P routing [q_local][s]

    const int tid = threadIdx.x;
    const int wid = tid >> 6, ln = tid & 63;
    const int q16 = ln & 15, g = ln >> 4, g8 = g * 8;

    const int id = blockIdx.x;
    const int bh = (id & 7) * 4 + ((id >> 3) & 3);   // XCD-chunked
    const int qsuper = id >> 5;
    const int b = bh >> 4, h = bh & 15;
    const bf16_t* Q  = qp  + (size_t)b * T * HC + (size_t)h * 64;
    const bf16_t* Kg = kp  + (size_t)b * T * HC + (size_t)h * 64;
    const bf16_t* Vt = vtp + (size_t)b * HC * T + (size_t)h * 64 * T;

    int qrow[2], qloc[2];
    bf16x8 qf[2][2];
#pragma unroll
    for (int st = 0; st < 2; ++st) {
        qloc[st] = wid * 16 + st * 64 + q16;
        qrow[st] = qsuper * 128 + qloc[st];
        qf[st][0] = *(const bf16x8*)(Q + (size_t)qrow[st] * HC + g8);
        qf[st][1] = *(const bf16x8*)(Q + (size_t)qrow[st] * HC + 32 + g8);
    }

    float m[2] = {-3.0e38f, -3.0e38f}, l[2] = {0.f, 0.f};
    f32x4 zero = {0.f, 0.f, 0.f, 0.f};
    f32x4 oacc[2][4];
#pragma unroll
    for (int st = 0; st < 2; ++st)
#pragma unroll
        for (int i = 0; i < 4; ++i) oacc[st][i] = zero;

    const int ntiles = qsuper + 1;
    int4 kreg[4], vreg[4];

    auto ldtile = [&](int t) {
        int kv = t * 128;
#pragma unroll
        for (int i = 0; i < 4; ++i) {
            int idx = tid + i * 256;
            kreg[i] = *(const int4*)(Kg + (size_t)(kv + (idx >> 3)) * HC + (idx & 7) * 8);
            vreg[i] = *(const int4*)(Vt + (size_t)(idx >> 4) * T + kv + (idx & 15) * 8);
        }
    };
    auto wrtile = [&]() {
#pragma unroll
        for (int i = 0; i < 4; ++i) {
            int idx = tid + i * 256;
            *(int4*)&Ks[idx >> 3][(idx & 7) * 8] = kreg[i];
            *(int4*)&Vs[idx >> 4][(idx & 15) * 8] = vreg[i];
        }
    };

    ldtile(0);
    wrtile();
    __syncthreads();

    for (int t = 0; t < ntiles; ++t) {
        const int kv0 = t * 128;
        if (t + 1 < ntiles) ldtile(t + 1);

        // --- QK^T (K frags shared between strips) ---
        float zs[2][8][4];
#pragma unroll
        for (int sb = 0; sb < 8; ++sb) {
            bf16x8 kf0 = *(const bf16x8*)&Ks[sb * 16 + q16][g8];
            bf16x8 kf1 = *(const bf16x8*)&Ks[sb * 16 + q16][32 + g8];
            int sbase = kv0 + sb * 16 + 4 * g;
#pragma unroll
            for (int st = 0; st < 2; ++st) {
                f32x4 z = zero;
                z = __builtin_amdgcn_mfma_f32_16x16x32_bf16(kf0, qf[st][0], z, 0, 0, 0);
                z = __builtin_amdgcn_mfma_f32_16x16x32_bf16(kf1, qf[st][1], z, 0, 0, 0);
                if (t == qsuper) {
#pragma unroll
                    for (int r = 0; r < 4; ++r)
                        zs[st][sb][r] = (sbase + r <= qrow[st]) ? z[r] * SC2 : -1.0e30f;
                } else {
#pragma unroll
                    for (int r = 0; r < 4; ++r) zs[st][sb][r] = z[r] * SC2;
                }
            }
        }

        // --- row max (per strip) + defer check ---
        float pm[2];
#pragma unroll
        for (int st = 0; st < 2; ++st) {
            float a0 = zs[st][0][0];
#pragma unroll
            for (int sb = 0; sb < 8; ++sb)
#pragma unroll
                for (int r = 0; r < 4; ++r) a0 = fmaxf(a0, zs[st][sb][r]);
            a0 = fmaxf(a0, __shfl_xor(a0, 16, 64));
            a0 = fmaxf(a0, __shfl_xor(a0, 32, 64));
            pm[st] = a0;
        }
        bool defer = (pm[0] <= m[0] + THR) && (pm[1] <= m[1] + THR);
        if (!__all((int)defer)) {
#pragma unroll
            for (int st = 0; st < 2; ++st) {
                float newm = fmaxf(m[st], pm[st]);
                float alpha = exp2f(m[st] - newm);
                m[st] = newm;
                l[st] *= alpha;
                float ar[4];
#pragma unroll
                for (int r = 0; r < 4; ++r) ar[r] = __shfl(alpha, 4 * g + r, 64);
#pragma unroll
                for (int nf = 0; nf < 4; ++nf)
#pragma unroll
                    for (int r = 0; r < 4; ++r) oacc[st][nf][r] *= ar[r];
            }
        }

        // --- exp, sum, pack -> Pex (wave-local rows) ---
#pragma unroll
        for (int st = 0; st < 2; ++st) {
            f32x4 ps4 = zero;
#pragma unroll
            for (int sb = 0; sb < 8; ++sb) {
                float e0 = exp2f(zs[st][sb][0] - m[st]);
                float e1 = exp2f(zs[st][sb][1] - m[st]);
                float e2 = exp2f(zs[st][sb][2] - m[st]);
                float e3 = exp2f(zs[st][sb][3] - m[st]);
                ps4[0] += e0; ps4[1] += e1; ps4[2] += e2; ps4[3] += e3;
                uint2 w;
                w.x = pk2(e0, e1);
                w.y = pk2(e2, e3);
                *(uint2*)&Pex[qloc[st]][sb * 16 + 4 * g] = w;
            }
            float psum = ps4[0] + ps4[1] + ps4[2] + ps4[3];
            psum += __shfl_xor(psum, 16, 64);
            psum += __shfl_xor(psum, 32, 64);
            l[st] += psum;
        }

        // --- PV (V frags shared between strips) ---
        bf16x8 pa[2][4];
#pragma unroll
        for (int st = 0; st < 2; ++st)
#pragma unroll
            for (int kc = 0; kc < 4; ++kc)
                pa[st][kc] = *(const bf16x8*)&Pex[qloc[st]][kc * 32 + g8];
#pragma unroll
        for (int kc = 0; kc < 4; ++kc)
#pragma unroll
            for (int nf = 0; nf < 4; ++nf) {
                bf16x8 vf = *(const bf16x8*)&Vs[nf * 16 + q16][kc * 32 + g8];
#pragma unroll
                for (int st = 0; st < 2; ++st)
                    oacc[st][nf] = __builtin_amdgcn_mfma_f32_16x16x32_bf16(
                        pa[st][kc], vf, oacc[st][nf], 0, 0, 0);
            }

        if (t + 1 < ntiles) {
            __syncthreads();
            wrtile();
            __syncthreads();
        }
    }

    bf16_t* O = op + (size_t)b * T * HC + (size_t)h * 64;
#pragma unroll
    for (int st = 0; st < 2; ++st) {
        int base = qsuper * 128 + st * 64 + wid * 16;
#pragma unroll
        for (int r = 0; r < 4; ++r) {
            float lr = __shfl(l[st], 4 * g + r, 64);
            float inv = 1.0f / lr;
#pragma unroll
            for (int nf = 0; nf < 4; ++nf)
                O[(size_t)(base + 4 * g + r) * HC + nf * 16 + q16] =
                    (bf16_t)(oacc[st][nf][r] * inv);
        }
    }
}

// ---------------------------------------------------------------------------

extern "C" void kernel_launch(void* const* d_in, const int* in_sizes, int n_in,
                              void* d_out, int out_size, void* d_ws, size_t ws_size,
                              hipStream_t stream) {
    const float* K_in = (const float*)d_in[0];
    const float* Q_in = (const float*)d_in[1];
    const float* V_in = (const float*)d_in[2];
    const float* Wk   = (const float*)d_in[3];
    const float* Wq   = (const float*)d_in[4];
    const float* Wv   = (const float*)d_in[5];
    const float* Wo   = (const float*)d_in[6];
    const float* bo   = (const float*)d_in[7];

    char* ws = (char*)d_ws;
    const size_t MB = 1024 * 1024;
    bf16_t* Wqt = (bf16_t*)(ws + 0 * MB);
    bf16_t* Wkt = (bf16_t*)(ws + 2 * MB);
    bf16_t* Wvt = (bf16_t*)(ws + 4 * MB);
    bf16_t* Wot = (bf16_t*)(ws + 6 * MB);
    bf16_t* qp  = (bf16_t*)(ws + 8 * MB);
    bf16_t* kp  = (bf16_t*)(ws + 16 * MB);
    bf16_t* vp  = (bf16_t*)(ws + 24 * MB);
    bf16_t* vt  = (bf16_t*)(ws + 32 * MB);
    bf16_t* ao  = (bf16_t*)(ws + 24 * MB);   // reuse vp after transpose

    conv_whead<<<1024, 256, 0, stream>>>(Wq, Wqt);
    conv_whead<<<1024, 256, 0, stream>>>(Wk, Wkt);
    conv_whead<<<1024, 256, 0, stream>>>(Wv, Wvt);
    conv_wo  <<<1024, 256, 0, stream>>>(Wo, Wot);

    gemm_proj<<<dim3(8, 32, 3), 256, 0, stream>>>(Q_in, K_in, V_in,
                                                  Wqt, Wkt, Wvt,
                                                  qp, kp, vp);

    transpose_bf16<<<dim3(32, 16, 2), 256, 0, stream>>>(vp, vt);

    attn_causal<<<512, 256, 0, stream>>>(qp, kp, vt, ao);

    gemm_out<<<dim3(8, 64), 256, 0, stream>>>(ao, Wot, d_out, bo);
}

// Round 5
// 197.577 us; speedup vs baseline: 1.5814x; 1.0856x over previous
//
#include <hip/hip_runtime.h>
#include <hip/hip_bf16.h>

typedef __bf16 bf16_t;
typedef __bf16 bf16x4 __attribute__((ext_vector_type(4)));
typedef __bf16 bf16x8 __attribute__((ext_vector_type(8)));
typedef float f32x4 __attribute__((ext_vector_type(4)));
typedef unsigned int u32;

static __device__ __forceinline__ u32 pk2(float a, float b) {
    union { u32 u; bf16_t h[2]; } w;
    w.h[0] = (bf16_t)a; w.h[1] = (bf16_t)b;
    return w.u;
}

// ---------------------------------------------------------------------------
// Weight conversion: fp32 -> bf16, to [N][K] (B^T) layout.
// ---------------------------------------------------------------------------
__global__ void conv_whead(const float* __restrict__ in, bf16_t* __restrict__ out) {
    int idx = blockIdx.x * 256 + threadIdx.x;
    int n  = idx >> 8;
    int c0 = (idx & 255) * 4;
    int h = n >> 6, d = n & 63;
    const float* s = in + (size_t)h * 65536 + d;
    bf16x4 v;
#pragma unroll
    for (int j = 0; j < 4; ++j) v[j] = (bf16_t)s[(size_t)(c0 + j) * 64];
    *(bf16x4*)(out + (size_t)n * 1024 + c0) = v;
}

__global__ void conv_wo(const float* __restrict__ in, bf16_t* __restrict__ out) {
    int idx = blockIdx.x * 256 + threadIdx.x;
    int n  = idx >> 8;
    int k0 = (idx & 255) * 4;
    bf16x4 v;
#pragma unroll
    for (int j = 0; j < 4; ++j) v[j] = (bf16_t)in[(size_t)(k0 + j) * 1024 + n];
    *(bf16x4*)(out + (size_t)n * 1024 + k0) = v;
}

// ---------------------------------------------------------------------------
// GEMM core: C[M][1024] = A[M][1024] @ Bt[1024][1024]^T (+bias)
// ---------------------------------------------------------------------------
template<int BM, bool A_F32, bool OUT_F32, bool BIAS>
__device__ __forceinline__
void gemm_core(const void* Ap, const bf16_t* Bt, void* Cp, const float* bias,
               int m0, int n0) {
    constexpr int N = 1024, K = 1024, BK = 32;
    constexpr int MI = BM / 32;
    constexpr int AL = BM / 64;
    __shared__ bf16_t As[2][BM][BK + 8];
    __shared__ bf16_t Bs[2][128][BK + 8];

    const int tid = threadIdx.x;
    const int wid = tid >> 6, ln = tid & 63;
    const int ln16 = ln & 15, g8 = (ln >> 4) * 8;
    const int wr = (wid >> 1) * (BM / 2), wc = (wid & 1) * 64;

    const float*  Af = (const float*)Ap;
    const bf16_t* Ab = (const bf16_t*)Ap;

    f32x4 zero = {0.f, 0.f, 0.f, 0.f};
    f32x4 acc[MI][4];
#pragma unroll
    for (int i = 0; i < MI; ++i)
#pragma unroll
        for (int j = 0; j < 4; ++j) acc[i][j] = zero;

    auto stage = [&](int buf, int k0) {
#pragma unroll
        for (int i = 0; i < AL; ++i) {
            int c = tid + i * 256;
            int row = c >> 2, k8 = (c & 3) * 8;
            if constexpr (A_F32) {
                const float* s = Af + (size_t)(m0 + row) * K + k0 + k8;
                float4 x0 = *(const float4*)s;
                float4 x1 = *(const float4*)(s + 4);
                bf16x8 v;
                v[0] = (bf16_t)x0.x; v[1] = (bf16_t)x0.y; v[2] = (bf16_t)x0.z; v[3] = (bf16_t)x0.w;
                v[4] = (bf16_t)x1.x; v[5] = (bf16_t)x1.y; v[6] = (bf16_t)x1.z; v[7] = (bf16_t)x1.w;
                *(bf16x8*)&As[buf][row][k8] = v;
            } else {
                *(int4*)&As[buf][row][k8] =
                    *(const int4*)(Ab + (size_t)(m0 + row) * K + k0 + k8);
            }
        }
#pragma unroll
        for (int i = 0; i < 2; ++i) {
            int c = tid + i * 256;
            int row = c >> 2, k8 = (c & 3) * 8;
            *(int4*)&Bs[buf][row][k8] =
                *(const int4*)(Bt + (size_t)(n0 + row) * K + k0 + k8);
        }
    };

    stage(0, 0);
    __syncthreads();
    for (int kt = 0; kt < K / BK; ++kt) {
        int cur = kt & 1;
        if (kt + 1 < K / BK) stage(cur ^ 1, (kt + 1) * BK);
        bf16x8 a[MI], b[4];
#pragma unroll
        for (int i = 0; i < MI; ++i)
            a[i] = *(const bf16x8*)&As[cur][wr + i * 16 + ln16][g8];
#pragma unroll
        for (int i = 0; i < 4; ++i)
            b[i] = *(const bf16x8*)&Bs[cur][wc + i * 16 + ln16][g8];
#pragma unroll
        for (int mi = 0; mi < MI; ++mi)
#pragma unroll
            for (int ni = 0; ni < 4; ++ni)
                acc[mi][ni] = __builtin_amdgcn_mfma_f32_16x16x32_bf16(
                    a[mi], b[ni], acc[mi][ni], 0, 0, 0);
        __syncthreads();
    }

    float*  Cf = (float*)Cp;
    bf16_t* Cb = (bf16_t*)Cp;
#pragma unroll
    for (int mi = 0; mi < MI; ++mi)
#pragma unroll
        for (int ni = 0; ni < 4; ++ni)
#pragma unroll
            for (int r = 0; r < 4; ++r) {
                int row = m0 + wr + mi * 16 + (ln >> 4) * 4 + r;
                int col = n0 + wc + ni * 16 + ln16;
                float v = acc[mi][ni][r];
                if constexpr (BIAS) v += bias[col];
                if constexpr (OUT_F32) Cf[(size_t)row * N + col] = v;
                else                   Cb[(size_t)row * N + col] = (bf16_t)v;
            }
}

__global__ __launch_bounds__(256, 3)
void gemm_proj(const float* A0, const float* A1, const float* A2,
               const bf16_t* B0, const bf16_t* B1, const bf16_t* B2,
               bf16_t* C0, bf16_t* C1, bf16_t* C2) {
    int z = blockIdx.z;
    const float* A = (z == 0) ? A0 : (z == 1) ? A1 : A2;
    const bf16_t* B = (z == 0) ? B0 : (z == 1) ? B1 : B2;
    bf16_t* C = (z == 0) ? C0 : (z == 1) ? C1 : C2;
    gemm_core<128, true, false, false>(A, B, C, nullptr,
                                       blockIdx.y * 128, blockIdx.x * 128);
}

__global__ __launch_bounds__(256, 4)
void gemm_out(const bf16_t* A, const bf16_t* Bt, void* C, const float* bias) {
    gemm_core<64, false, true, true>(A, Bt, C, bias,
                                     blockIdx.y * 64, blockIdx.x * 128);
}

// ---------------------------------------------------------------------------
// Transpose v [B][T][HC] -> vt [B][HC][T]
// ---------------------------------------------------------------------------
__global__ void transpose_bf16(const bf16_t* __restrict__ in, bf16_t* __restrict__ out) {
    __shared__ bf16_t t[64][72];
    const int b = blockIdx.z;
    const int r0 = blockIdx.x * 64;
    const int c0 = blockIdx.y * 64;
    const bf16_t* src = in + (size_t)b * 2048 * 1024;
    bf16_t* dst = out + (size_t)b * 1024 * 2048;
    const int tid = threadIdx.x;
    const int row = tid >> 3, c8 = (tid & 7) * 8;
#pragma unroll
    for (int i = 0; i < 2; ++i)
        *(int4*)&t[row + i * 32][c8] =
            *(const int4*)(src + (size_t)(r0 + row + i * 32) * 1024 + c0 + c8);
    __syncthreads();
#pragma unroll
    for (int i = 0; i < 2; ++i) {
        int orow = row + i * 32;
        bf16x8 v;
#pragma unroll
        for (int j = 0; j < 8; ++j) v[j] = t[c8 + j][orow];
        *(bf16x8*)(dst + (size_t)(c0 + orow) * 2048 + r0 + c8) = v;
    }
}

// ---------------------------------------------------------------------------
// Causal flash attention v3: barrier-free, fully independent waves.
// K/V fragments loaded directly from global (L2-resident per bh; all blocks
// of one bh land on one XCD since bh = blockIdx.x & 31 and 32 % 8 == 0).
// Wave = 32 q-rows (2 strips of 16), KVBLK = 64.
// Balance: blocks c and c+256 (co-resident on the same CU, same SIMD slots)
// carry strips g and 63-g -> every SIMD's two waves total exactly 33 tiles.
// P routing via wave-private XOR-swizzled LDS (2-way banks = free).
// ---------------------------------------------------------------------------
__global__ __launch_bounds__(256, 2)
void attn_causal(const bf16_t* __restrict__ qp, const bf16_t* __restrict__ kp,
                 const bf16_t* __restrict__ vtp, bf16_t* __restrict__ op) {
    constexpr int T = 2048, HC = 1024;
    constexpr float SC2 = 0.18033688011112042f;   // 0.125 * log2(e)
    constexpr float THR = 7.0f;
    __shared__ u32 Pex[4][32][32];   // [wave][q_local][u32 col], XOR-swizzled

    const int tid = threadIdx.x;
    const int wid = tid >> 6, ln = tid & 63;
    const int q16 = ln & 15, g = ln >> 4, g8 = g * 8;
    const u32 swz = (u32)(q16 & 7) << 2;   // XOR on u32-col bits 2..4

    const int c = blockIdx.x;
    const int bh = c & 31;
    const int j = (c >> 5) & 7;
    const int half = (c >> 8) & 1;
    const int gidx = j * 4 + wid;
    const int strip = half ? (63 - gidx) : gidx;   // 0..63
    const int qbase = strip * 32;
    const int ntiles = strip / 2 + 1;

    const int b = bh >> 4, h = bh & 15;
    const bf16_t* Q  = qp  + (size_t)b * T * HC + (size_t)h * 64;
    const bf16_t* Kg = kp  + (size_t)b * T * HC + (size_t)h * 64;
    const bf16_t* Vt = vtp + (size_t)b * HC * T + (size_t)h * 64 * T;

    int qrow[2];
    bf16x8 qf[2][2];
#pragma unroll
    for (int st = 0; st < 2; ++st) {
        qrow[st] = qbase + st * 16 + q16;
        qf[st][0] = *(const bf16x8*)(Q + (size_t)qrow[st] * HC + g8);
        qf[st][1] = *(const bf16x8*)(Q + (size_t)qrow[st] * HC + 32 + g8);
    }

    float m[2] = {-3.0e38f, -3.0e38f}, l[2] = {0.f, 0.f};
    f32x4 zero = {0.f, 0.f, 0.f, 0.f};
    f32x4 oacc[2][4];
#pragma unroll
    for (int st = 0; st < 2; ++st)
#pragma unroll
        for (int i = 0; i < 4; ++i) oacc[st][i] = zero;

    for (int t = 0; t < ntiles; ++t) {
        const int kv0 = t * 64;
        const bool last = (t == ntiles - 1);

        // --- QK^T: K-fragments direct from global (one full 128B line/row) ---
        float zs[2][4][4];
        __builtin_amdgcn_s_setprio(1);
#pragma unroll
        for (int sb = 0; sb < 4; ++sb) {
            const bf16_t* kr = Kg + (size_t)(kv0 + sb * 16 + q16) * HC;
            bf16x8 kf0 = *(const bf16x8*)(kr + g8);
            bf16x8 kf1 = *(const bf16x8*)(kr + 32 + g8);
            int sbase = kv0 + sb * 16 + 4 * g;
#pragma unroll
            for (int st = 0; st < 2; ++st) {
                f32x4 z = zero;
                z = __builtin_amdgcn_mfma_f32_16x16x32_bf16(kf0, qf[st][0], z, 0, 0, 0);
                z = __builtin_amdgcn_mfma_f32_16x16x32_bf16(kf1, qf[st][1], z, 0, 0, 0);
                if (last) {
#pragma unroll
                    for (int r = 0; r < 4; ++r)
                        zs[st][sb][r] = (sbase + r <= qrow[st]) ? z[r] * SC2 : -1.0e30f;
                } else {
#pragma unroll
                    for (int r = 0; r < 4; ++r) zs[st][sb][r] = z[r] * SC2;
                }
            }
        }
        __builtin_amdgcn_s_setprio(0);

        // --- V fragments hoisted: latency hides under softmax ---
        bf16x8 vfr[2][4];
#pragma unroll
        for (int kc = 0; kc < 2; ++kc)
#pragma unroll
            for (int nf = 0; nf < 4; ++nf)
                vfr[kc][nf] = *(const bf16x8*)(Vt + (size_t)(nf * 16 + q16) * T
                                               + kv0 + kc * 32 + g8);

        // --- online softmax (per strip), defer-max ---
        float pm[2];
#pragma unroll
        for (int st = 0; st < 2; ++st) {
            float a0 = zs[st][0][0];
#pragma unroll
            for (int sb = 0; sb < 4; ++sb)
#pragma unroll
                for (int r = 0; r < 4; ++r) a0 = fmaxf(a0, zs[st][sb][r]);
            a0 = fmaxf(a0, __shfl_xor(a0, 16, 64));
            a0 = fmaxf(a0, __shfl_xor(a0, 32, 64));
            pm[st] = a0;
        }
        bool defer = (pm[0] <= m[0] + THR) && (pm[1] <= m[1] + THR);
        if (!__all((int)defer)) {
#pragma unroll
            for (int st = 0; st < 2; ++st) {
                float newm = fmaxf(m[st], pm[st]);
                float alpha = exp2f(m[st] - newm);
                m[st] = newm;
                l[st] *= alpha;
                float ar[4];
#pragma unroll
                for (int r = 0; r < 4; ++r) ar[r] = __shfl(alpha, 4 * g + r, 64);
#pragma unroll
                for (int nf = 0; nf < 4; ++nf)
#pragma unroll
                    for (int r = 0; r < 4; ++r) oacc[st][nf][r] *= ar[r];
            }
        }

        // --- exp2, row-sum, pack -> wave-private swizzled Pex ---
#pragma unroll
        for (int st = 0; st < 2; ++st) {
            f32x4 ps4 = zero;
#pragma unroll
            for (int sb = 0; sb < 4; ++sb) {
                float e0 = exp2f(zs[st][sb][0] - m[st]);
                float e1 = exp2f(zs[st][sb][1] - m[st]);
                float e2 = exp2f(zs[st][sb][2] - m[st]);
                float e3 = exp2f(zs[st][sb][3] - m[st]);
                ps4[0] += e0; ps4[1] += e1; ps4[2] += e2; ps4[3] += e3;
                uint2 w;
                w.x = pk2(e0, e1);
                w.y = pk2(e2, e3);
                u32 colA = ((u32)(sb * 8 + 2 * g)) ^ swz;   // even -> 8B aligned
                *(uint2*)&Pex[wid][st * 16 + q16][colA] = w;
            }
            float psum = ps4[0] + ps4[1] + ps4[2] + ps4[3];
            psum += __shfl_xor(psum, 16, 64);
            psum += __shfl_xor(psum, 32, 64);
            l[st] += psum;
        }

        // --- PV: A-frags from own Pex row (swizzled, aligned 16B group) ---
        __builtin_amdgcn_s_setprio(1);
#pragma unroll
        for (int kc = 0; kc < 2; ++kc) {
            bf16x8 pa[2];
#pragma unroll
            for (int st = 0; st < 2; ++st) {
                u32 colR = ((u32)(kc * 16 + 4 * g)) ^ swz;   // mult of 4
                pa[st] = *(const bf16x8*)&Pex[wid][st * 16 + q16][colR];
            }
#pragma unroll
            for (int nf = 0; nf < 4; ++nf)
#pragma unroll
                for (int st = 0; st < 2; ++st)
                    oacc[st][nf] = __builtin_amdgcn_mfma_f32_16x16x32_bf16(
                        pa[st], vfr[kc][nf], oacc[st][nf], 0, 0, 0);
        }
        __builtin_amdgcn_s_setprio(0);
    }

    bf16_t* O = op + (size_t)b * T * HC + (size_t)h * 64;
#pragma unroll
    for (int st = 0; st < 2; ++st) {
        int base = qbase + st * 16;
#pragma unroll
        for (int r = 0; r < 4; ++r) {
            float lr = __shfl(l[st], 4 * g + r, 64);
            float inv = 1.0f / lr;
#pragma unroll
            for (int nf = 0; nf < 4; ++nf)
                O[(size_t)(base + 4 * g + r) * HC + nf * 16 + q16] =
                    (bf16_t)(oacc[st][nf][r] * inv);
        }
    }
}

// ---------------------------------------------------------------------------

extern "C" void kernel_launch(void* const* d_in, const int* in_sizes, int n_in,
                              void* d_out, int out_size, void* d_ws, size_t ws_size,
                              hipStream_t stream) {
    const float* K_in = (const float*)d_in[0];
    const float* Q_in = (const float*)d_in[1];
    const float* V_in = (const float*)d_in[2];
    const float* Wk   = (const float*)d_in[3];
    const float* Wq   = (const float*)d_in[4];
    const float* Wv   = (const float*)d_in[5];
    const float* Wo   = (const float*)d_in[6];
    const float* bo   = (const float*)d_in[7];

    char* ws = (char*)d_ws;
    const size_t MB = 1024 * 1024;
    bf16_t* Wqt = (bf16_t*)(ws + 0 * MB);
    bf16_t* Wkt = (bf16_t*)(ws + 2 * MB);
    bf16_t* Wvt = (bf16_t*)(ws + 4 * MB);
    bf16_t* Wot = (bf16_t*)(ws + 6 * MB);
    bf16_t* qp  = (bf16_t*)(ws + 8 * MB);
    bf16_t* kp  = (bf16_t*)(ws + 16 * MB);
    bf16_t* vp  = (bf16_t*)(ws + 24 * MB);
    bf16_t* vt  = (bf16_t*)(ws + 32 * MB);
    bf16_t* ao  = (bf16_t*)(ws + 24 * MB);   // reuse vp after transpose

    conv_whead<<<1024, 256, 0, stream>>>(Wq, Wqt);
    conv_whead<<<1024, 256, 0, stream>>>(Wk, Wkt);
    conv_whead<<<1024, 256, 0, stream>>>(Wv, Wvt);
    conv_wo  <<<1024, 256, 0, stream>>>(Wo, Wot);

    gemm_proj<<<dim3(8, 32, 3), 256, 0, stream>>>(Q_in, K_in, V_in,
                                                  Wqt, Wkt, Wvt,
                                                  qp, kp, vp);

    transpose_bf16<<<dim3(32, 16, 2), 256, 0, stream>>>(vp, vt);

    attn_causal<<<512, 256, 0, stream>>>(qp, kp, vt, ao);

    gemm_out<<<dim3(8, 64), 256, 0, stream>>>(ao, Wot, d_out, bo);
}

// Round 9
// 185.927 us; speedup vs baseline: 1.6804x; 1.0627x over previous
//
#include <hip/hip_runtime.h>
#include <hip/hip_bf16.h>

typedef __bf16 bf16_t;
typedef __bf16 bf16x4 __attribute__((ext_vector_type(4)));
typedef __bf16 bf16x8 __attribute__((ext_vector_type(8)));
typedef float f32x4 __attribute__((ext_vector_type(4)));
typedef unsigned int u32;

static __device__ __forceinline__ u32 pk2(float a, float b) {
    union { u32 u; bf16_t h[2]; } w;
    w.h[0] = (bf16_t)a; w.h[1] = (bf16_t)b;
    return w.u;
}

#define GLOAD_LDS16(gsrc, ldst)                                                  \
    __builtin_amdgcn_global_load_lds(                                            \
        (const __attribute__((address_space(1))) void*)(gsrc),                   \
        (__attribute__((address_space(3))) void*)(ldst), 16, 0, 0)

// ---------------------------------------------------------------------------
// Weight transpose-converts (LDS 64x64 tiles, coalesced both sides).
// Validated bit-exact vs r5 convs by the r7/r8 identical-absmax evidence.
// ---------------------------------------------------------------------------
__global__ void conv_whead_t(const float* __restrict__ in, bf16_t* __restrict__ out) {
    __shared__ bf16_t t[64][72];
    const int tc = blockIdx.x, h = blockIdx.y;
    const int tid = threadIdx.x;
#pragma unroll
    for (int p = 0; p < 4; ++p) {
        int r = p * 16 + (tid >> 4);          // c-local
        int c4 = (tid & 15) * 4;              // d-local
        float4 x = *(const float4*)(in + (size_t)h * 65536 + (size_t)(tc * 64 + r) * 64 + c4);
        t[r][c4 + 0] = (bf16_t)x.x; t[r][c4 + 1] = (bf16_t)x.y;
        t[r][c4 + 2] = (bf16_t)x.z; t[r][c4 + 3] = (bf16_t)x.w;
    }
    __syncthreads();
#pragma unroll
    for (int p = 0; p < 2; ++p) {
        int d = p * 32 + (tid >> 3);
        int c8 = (tid & 7) * 8;
        bf16x8 v;
#pragma unroll
        for (int j = 0; j < 8; ++j) v[j] = t[c8 + j][d];
        *(bf16x8*)(out + (size_t)(h * 64 + d) * 1024 + tc * 64 + c8) = v;
    }
}

__global__ void conv_wo_t(const float* __restrict__ in, bf16_t* __restrict__ out) {
    __shared__ bf16_t t[64][72];
    const int r0 = blockIdx.x * 64;   // k
    const int c0 = blockIdx.y * 64;   // n
    const int tid = threadIdx.x;
#pragma unroll
    for (int p = 0; p < 4; ++p) {
        int r = p * 16 + (tid >> 4);
        int c4 = (tid & 15) * 4;
        float4 x = *(const float4*)(in + (size_t)(r0 + r) * 1024 + c0 + c4);
        t[r][c4 + 0] = (bf16_t)x.x; t[r][c4 + 1] = (bf16_t)x.y;
        t[r][c4 + 2] = (bf16_t)x.z; t[r][c4 + 3] = (bf16_t)x.w;
    }
    __syncthreads();
#pragma unroll
    for (int p = 0; p < 2; ++p) {
        int d = p * 32 + (tid >> 3);   // n-local
        int c8 = (tid & 7) * 8;        // k-local
        bf16x8 v;
#pragma unroll
        for (int j = 0; j < 8; ++j) v[j] = t[c8 + j][d];
        *(bf16x8*)(out + (size_t)(c0 + d) * 1024 + r0 + c8) = v;
    }
}

// ---------------------------------------------------------------------------
// GEMM (r7 hybrid, validated): C[M][1024] = A[M][1024] @ Bt^T (+bias).
// 128x128 tile, BK=32, dbuf. B via global_load_lds (linear LDS); A fp32
// reg-staged into padded LDS, A bf16 via global_load_lds.
// ---------------------------------------------------------------------------
template<bool A_F32, bool OUT_F32, bool BIAS>
__device__ __forceinline__
void gemm_core(const void* Ap, const bf16_t* Bt, void* Cp, const float* bias,
               int m0, int n0) {
    constexpr int N = 1024, K = 1024, BK = 32;
    constexpr int APAD = A_F32 ? 8 : 0;
    __shared__ bf16_t As[2][128][BK + APAD];
    __shared__ bf16_t Bs[2][128][BK];

    const int tid = threadIdx.x;
    const int wv = tid >> 6, l = tid & 63;
    const int ln16 = l & 15, g8 = (l >> 4) * 8;
    const int wr = (wv >> 1) * 64, wc = (wv & 1) * 64;
    const int srow = l >> 2, scol = (l & 3) * 8;

    const float*  Af = (const float*)Ap;
    const bf16_t* Ab = (const bf16_t*)Ap;

    f32x4 zero = {0.f, 0.f, 0.f, 0.f};
    f32x4 acc[4][4];
#pragma unroll
    for (int i = 0; i < 4; ++i)
#pragma unroll
        for (int j = 0; j < 4; ++j) acc[i][j] = zero;

    auto stage = [&](int buf, int k0) {
#pragma unroll
        for (int i = 0; i < 2; ++i) {
            int row = wv * 32 + i * 16;
            if constexpr (A_F32) {
                const float* s = Af + (size_t)(m0 + row + srow) * K + k0 + scol;
                float4 x0 = *(const float4*)s;
                float4 x1 = *(const float4*)(s + 4);
                bf16x8 v;
                v[0] = (bf16_t)x0.x; v[1] = (bf16_t)x0.y; v[2] = (bf16_t)x0.z; v[3] = (bf16_t)x0.w;
                v[4] = (bf16_t)x1.x; v[5] = (bf16_t)x1.y; v[6] = (bf16_t)x1.z; v[7] = (bf16_t)x1.w;
                *(bf16x8*)&As[buf][row + srow][scol] = v;
            } else {
                GLOAD_LDS16(Ab + (size_t)(m0 + row + srow) * K + k0 + scol,
                            &As[buf][row][0]);
            }
            GLOAD_LDS16(Bt + (size_t)(n0 + row + srow) * K + k0 + scol,
                        &Bs[buf][row][0]);
        }
    };

    stage(0, 0);
    __syncthreads();
    for (int kt = 0; kt < K / BK; ++kt) {
        int cur = kt & 1;
        if (kt + 1 < K / BK) stage(cur ^ 1, (kt + 1) * BK);
        bf16x8 a[4], b[4];
#pragma unroll
        for (int i = 0; i < 4; ++i) {
            a[i] = *(const bf16x8*)&As[cur][wr + i * 16 + ln16][g8];
            b[i] = *(const bf16x8*)&Bs[cur][wc + i * 16 + ln16][g8];
        }
#pragma unroll
        for (int mi = 0; mi < 4; ++mi)
#pragma unroll
            for (int ni = 0; ni < 4; ++ni)
                acc[mi][ni] = __builtin_amdgcn_mfma_f32_16x16x32_bf16(
                    a[mi], b[ni], acc[mi][ni], 0, 0, 0);
        __syncthreads();
    }

    float*  Cf = (float*)Cp;
    bf16_t* Cb = (bf16_t*)Cp;
#pragma unroll
    for (int mi = 0; mi < 4; ++mi)
#pragma unroll
        for (int ni = 0; ni < 4; ++ni)
#pragma unroll
            for (int r = 0; r < 4; ++r) {
                int row = m0 + wr + mi * 16 + (l >> 4) * 4 + r;
                int col = n0 + wc + ni * 16 + ln16;
                float v = acc[mi][ni][r];
                if constexpr (BIAS) v += bias[col];
                if constexpr (OUT_F32) Cf[(size_t)row * N + col] = v;
                else                   Cb[(size_t)row * N + col] = (bf16_t)v;
            }
}

__global__ __launch_bounds__(256, 2)
void gemm_proj(const float* A0, const float* A1, const float* A2,
               const bf16_t* B0, const bf16_t* B1, const bf16_t* B2,
               bf16_t* C0, bf16_t* C1, bf16_t* C2) {
    int z = blockIdx.z;
    const float* A = (z == 0) ? A0 : (z == 1) ? A1 : A2;
    const bf16_t* B = (z == 0) ? B0 : (z == 1) ? B1 : B2;
    bf16_t* C = (z == 0) ? C0 : (z == 1) ? C1 : C2;
    gemm_core<true, false, false>(A, B, C, nullptr, blockIdx.y * 128, blockIdx.x * 128);
}

__global__ __launch_bounds__(256, 2)
void gemm_out(const bf16_t* A, const bf16_t* Bt, void* C, const float* bias) {
    gemm_core<false, true, true>(A, Bt, C, bias, blockIdx.y * 128, blockIdx.x * 128);
}

// ---------------------------------------------------------------------------
// Transpose v [B][T][HC] -> vt [B][HC][T]  (r5 exact)
// ---------------------------------------------------------------------------
__global__ void transpose_bf16(const bf16_t* __restrict__ in, bf16_t* __restrict__ out) {
    __shared__ bf16_t t[64][72];
    const int b = blockIdx.z;
    const int r0 = blockIdx.x * 64;
    const int c0 = blockIdx.y * 64;
    const bf16_t* src = in + (size_t)b * 2048 * 1024;
    bf16_t* dst = out + (size_t)b * 1024 * 2048;
    const int tid = threadIdx.x;
    const int row = tid >> 3, c8 = (tid & 7) * 8;
#pragma unroll
    for (int i = 0; i < 2; ++i)
        *(int4*)&t[row + i * 32][c8] =
            *(const int4*)(src + (size_t)(r0 + row + i * 32) * 1024 + c0 + c8);
    __syncthreads();
#pragma unroll
    for (int i = 0; i < 2; ++i) {
        int orow = row + i * 32;
        bf16x8 v;
#pragma unroll
        for (int j = 0; j < 8; ++j) v[j] = t[c8 + j][orow];
        *(bf16x8*)(dst + (size_t)(c0 + orow) * 2048 + r0 + c8) = v;
    }
}

// ---------------------------------------------------------------------------
// Causal flash attention v3 (r5 EXACT, passing): barrier-free independent
// waves, K/V fragments direct from global, wave-private swizzled P routing.
// ---------------------------------------------------------------------------
__global__ __launch_bounds__(256, 2)
void attn_causal(const bf16_t* __restrict__ qp, const bf16_t* __restrict__ kp,
                 const bf16_t* __restrict__ vtp, bf16_t* __restrict__ op) {
    constexpr int T = 2048, HC = 1024;
    constexpr float SC2 = 0.18033688011112042f;   // 0.125 * log2(e)
    constexpr float THR = 7.0f;
    __shared__ u32 Pex[4][32][32];   // [wave][q_local][u32 col], XOR-swizzled

    const int tid = threadIdx.x;
    const int wid = tid >> 6, ln = tid & 63;
    const int q16 = ln & 15, g = ln >> 4, g8 = g * 8;
    const u32 swz = (u32)(q16 & 7) << 2;   // XOR on u32-col bits 2..4

    const int c = blockIdx.x;
    const int bh = c & 31;
    const int j = (c >> 5) & 7;
    const int half = (c >> 8) & 1;
    const int gidx = j * 4 + wid;
    const int strip = half ? (63 - gidx) : gidx;   // 0..63
    const int qbase = strip * 32;
    const int ntiles = strip / 2 + 1;

    const int b = bh >> 4, h = bh & 15;
    const bf16_t* Q  = qp  + (size_t)b * T * HC + (size_t)h * 64;
    const bf16_t* Kg = kp  + (size_t)b * T * HC + (size_t)h * 64;
    const bf16_t* Vt = vtp + (size_t)b * HC * T + (size_t)h * 64 * T;

    int qrow[2];
    bf16x8 qf[2][2];
#pragma unroll
    for (int st = 0; st < 2; ++st) {
        qrow[st] = qbase + st * 16 + q16;
        qf[st][0] = *(const bf16x8*)(Q + (size_t)qrow[st] * HC + g8);
        qf[st][1] = *(const bf16x8*)(Q + (size_t)qrow[st] * HC + 32 + g8);
    }

    float m[2] = {-3.0e38f, -3.0e38f}, l[2] = {0.f, 0.f};
    f32x4 zero = {0.f, 0.f, 0.f, 0.f};
    f32x4 oacc[2][4];
#pragma unroll
    for (int st = 0; st < 2; ++st)
#pragma unroll
        for (int i = 0; i < 4; ++i) oacc[st][i] = zero;

    for (int t = 0; t < ntiles; ++t) {
        const int kv0 = t * 64;
        const bool last = (t == ntiles - 1);

        // --- QK^T: K-fragments direct from global (one full 128B line/row) ---
        float zs[2][4][4];
        __builtin_amdgcn_s_setprio(1);
#pragma unroll
        for (int sb = 0; sb < 4; ++sb) {
            const bf16_t* kr = Kg + (size_t)(kv0 + sb * 16 + q16) * HC;
            bf16x8 kf0 = *(const bf16x8*)(kr + g8);
            bf16x8 kf1 = *(const bf16x8*)(kr + 32 + g8);
            int sbase = kv0 + sb * 16 + 4 * g;
#pragma unroll
            for (int st = 0; st < 2; ++st) {
                f32x4 z = zero;
                z = __builtin_amdgcn_mfma_f32_16x16x32_bf16(kf0, qf[st][0], z, 0, 0, 0);
                z = __builtin_amdgcn_mfma_f32_16x16x32_bf16(kf1, qf[st][1], z, 0, 0, 0);
                if (last) {
#pragma unroll
                    for (int r = 0; r < 4; ++r)
                        zs[st][sb][r] = (sbase + r <= qrow[st]) ? z[r] * SC2 : -1.0e30f;
                } else {
#pragma unroll
                    for (int r = 0; r < 4; ++r) zs[st][sb][r] = z[r] * SC2;
                }
            }
        }
        __builtin_amdgcn_s_setprio(0);

        // --- V fragments hoisted: latency hides under softmax ---
        bf16x8 vfr[2][4];
#pragma unroll
        for (int kc = 0; kc < 2; ++kc)
#pragma unroll
            for (int nf = 0; nf < 4; ++nf)
                vfr[kc][nf] = *(const bf16x8*)(Vt + (size_t)(nf * 16 + q16) * T
                                               + kv0 + kc * 32 + g8);

        // --- online softmax (per strip), defer-max ---
        float pm[2];
#pragma unroll
        for (int st = 0; st < 2; ++st) {
            float a0 = zs[st][0][0];
#pragma unroll
            for (int sb = 0; sb < 4; ++sb)
#pragma unroll
                for (int r = 0; r < 4; ++r) a0 = fmaxf(a0, zs[st][sb][r]);
            a0 = fmaxf(a0, __shfl_xor(a0, 16, 64));
            a0 = fmaxf(a0, __shfl_xor(a0, 32, 64));
            pm[st] = a0;
        }
        bool defer = (pm[0] <= m[0] + THR) && (pm[1] <= m[1] + THR);
        if (!__all((int)defer)) {
#pragma unroll
            for (int st = 0; st < 2; ++st) {
                float newm = fmaxf(m[st], pm[st]);
                float alpha = exp2f(m[st] - newm);
                m[st] = newm;
                l[st] *= alpha;
                float ar[4];
#pragma unroll
                for (int r = 0; r < 4; ++r) ar[r] = __shfl(alpha, 4 * g + r, 64);
#pragma unroll
                for (int nf = 0; nf < 4; ++nf)
#pragma unroll
                    for (int r = 0; r < 4; ++r) oacc[st][nf][r] *= ar[r];
            }
        }

        // --- exp2, row-sum, pack -> wave-private swizzled Pex ---
#pragma unroll
        for (int st = 0; st < 2; ++st) {
            f32x4 ps4 = zero;
#pragma unroll
            for (int sb = 0; sb < 4; ++sb) {
                float e0 = exp2f(zs[st][sb][0] - m[st]);
                float e1 = exp2f(zs[st][sb][1] - m[st]);
                float e2 = exp2f(zs[st][sb][2] - m[st]);
                float e3 = exp2f(zs[st][sb][3] - m[st]);
                ps4[0] += e0; ps4[1] += e1; ps4[2] += e2; ps4[3] += e3;
                uint2 w;
                w.x = pk2(e0, e1);
                w.y = pk2(e2, e3);
                u32 colA = ((u32)(sb * 8 + 2 * g)) ^ swz;   // even -> 8B aligned
                *(uint2*)&Pex[wid][st * 16 + q16][colA] = w;
            }
            float psum = ps4[0] + ps4[1] + ps4[2] + ps4[3];
            psum += __shfl_xor(psum, 16, 64);
            psum += __shfl_xor(psum, 32, 64);
            l[st] += psum;
        }

        // --- PV: A-frags from own Pex row (swizzled, aligned 16B group) ---
        __builtin_amdgcn_s_setprio(1);
#pragma unroll
        for (int kc = 0; kc < 2; ++kc) {
            bf16x8 pa[2];
#pragma unroll
            for (int st = 0; st < 2; ++st) {
                u32 colR = ((u32)(kc * 16 + 4 * g)) ^ swz;   // mult of 4
                pa[st] = *(const bf16x8*)&Pex[wid][st * 16 + q16][colR];
            }
#pragma unroll
            for (int nf = 0; nf < 4; ++nf)
#pragma unroll
                for (int st = 0; st < 2; ++st)
                    oacc[st][nf] = __builtin_amdgcn_mfma_f32_16x16x32_bf16(
                        pa[st], vfr[kc][nf], oacc[st][nf], 0, 0, 0);
        }
        __builtin_amdgcn_s_setprio(0);
    }

    bf16_t* O = op + (size_t)b * T * HC + (size_t)h * 64;
#pragma unroll
    for (int st = 0; st < 2; ++st) {
        int base = qbase + st * 16;
#pragma unroll
        for (int r = 0; r < 4; ++r) {
            float lr = __shfl(l[st], 4 * g + r, 64);
            float inv = 1.0f / lr;
#pragma unroll
            for (int nf = 0; nf < 4; ++nf)
                O[(size_t)(base + 4 * g + r) * HC + nf * 16 + q16] =
                    (bf16_t)(oacc[st][nf][r] * inv);
        }
    }
}

// ---------------------------------------------------------------------------

extern "C" void kernel_launch(void* const* d_in, const int* in_sizes, int n_in,
                              void* d_out, int out_size, void* d_ws, size_t ws_size,
                              hipStream_t stream) {
    const float* K_in = (const float*)d_in[0];
    const float* Q_in = (const float*)d_in[1];
    const float* V_in = (const float*)d_in[2];
    const float* Wk   = (const float*)d_in[3];
    const float* Wq   = (const float*)d_in[4];
    const float* Wv   = (const float*)d_in[5];
    const float* Wo   = (const float*)d_in[6];
    const float* bo   = (const float*)d_in[7];

    // 40 MB workspace layout (r5 exact)
    char* ws = (char*)d_ws;
    const size_t MB = 1024 * 1024;
    bf16_t* Wqt = (bf16_t*)(ws + 0 * MB);
    bf16_t* Wkt = (bf16_t*)(ws + 2 * MB);
    bf16_t* Wvt = (bf16_t*)(ws + 4 * MB);
    bf16_t* Wot = (bf16_t*)(ws + 6 * MB);
    bf16_t* qp  = (bf16_t*)(ws + 8 * MB);
    bf16_t* kp  = (bf16_t*)(ws + 16 * MB);
    bf16_t* vp  = (bf16_t*)(ws + 24 * MB);
    bf16_t* vt  = (bf16_t*)(ws + 32 * MB);
    bf16_t* ao  = (bf16_t*)(ws + 24 * MB);   // reuse vp after transpose

    conv_whead_t<<<dim3(16, 16), 256, 0, stream>>>(Wq, Wqt);
    conv_whead_t<<<dim3(16, 16), 256, 0, stream>>>(Wk, Wkt);
    conv_whead_t<<<dim3(16, 16), 256, 0, stream>>>(Wv, Wvt);
    conv_wo_t<<<dim3(16, 16), 256, 0, stream>>>(Wo, Wot);

    gemm_proj<<<dim3(8, 32, 3), 256, 0, stream>>>(Q_in, K_in, V_in,
                                                  Wqt, Wkt, Wvt,
                                                  qp, kp, vp);

    transpose_bf16<<<dim3(32, 16, 2), 256, 0, stream>>>(vp, vt);

    attn_causal<<<512, 256, 0, stream>>>(qp, kp, vt, ao);

    gemm_out<<<dim3(8, 32), 256, 0, stream>>>(ao, Wot, d_out, bo);
}